// Round 1
// baseline (63.072 us; speedup 1.0000x reference)
//
#include <hip/hip_runtime.h>

#define EMB_DIM 4096

__global__ __launch_bounds__(256) void qembed_kernel(
    const int* __restrict__ ids,
    const int* __restrict__ weight,       // packed int4 pairs, widened to int32 (0..255)
    const float* __restrict__ scale,
    float* __restrict__ out,
    int n_tokens)
{
    const int token = blockIdx.x;
    if (token >= n_tokens) return;

    const int id = ids[token];
    const long long wrow = (long long)(id >> 1) * EMB_DIM;   // packed row (two ids per row)
    const long long srow = (long long)(id >> 5) * EMB_DIM;   // group row (GROUP_SIZE=32)
    const int shift = (id & 1) * 4;                          // low nibble for even, high for odd
    const long long obase = (long long)token * EMB_DIM;

    int f = threadIdx.x * 4;                                 // 256 thr * 4 elems = 1024/iter
    #pragma unroll
    for (int it = 0; it < 4; ++it, f += 1024) {
        int4  w = *reinterpret_cast<const int4*>(&weight[wrow + f]);
        float4 s = *reinterpret_cast<const float4*>(&scale[srow + f]);
        float4 o;
        o.x = (float)(((w.x >> shift) & 15) - 8) * s.x;
        o.y = (float)(((w.y >> shift) & 15) - 8) * s.y;
        o.z = (float)(((w.z >> shift) & 15) - 8) * s.z;
        o.w = (float)(((w.w >> shift) & 15) - 8) * s.w;
        *reinterpret_cast<float4*>(&out[obase + f]) = o;
    }
}

extern "C" void kernel_launch(void* const* d_in, const int* in_sizes, int n_in,
                              void* d_out, int out_size, void* d_ws, size_t ws_size,
                              hipStream_t stream) {
    const int*   ids    = (const int*)d_in[0];
    const int*   weight = (const int*)d_in[1];
    const float* scale  = (const float*)d_in[2];
    float*       out    = (float*)d_out;

    const int n_tokens = in_sizes[0];          // 4 * 2048 = 8192
    qembed_kernel<<<n_tokens, 256, 0, stream>>>(ids, weight, scale, out, n_tokens);
}

// Round 2
// 61.379 us; speedup vs baseline: 1.0276x; 1.0276x over previous
//
#include <hip/hip_runtime.h>

#define EMB_DIM 4096

__global__ __launch_bounds__(256) void qembed_kernel(
    const int* __restrict__ ids,
    const int* __restrict__ weight,       // packed int4 pairs, widened to int32 (0..255)
    const float* __restrict__ scale,
    float* __restrict__ out,
    int n_tokens)
{
    const int token = blockIdx.x;
    if (token >= n_tokens) return;

    const int id = ids[token];
    const long long wrow = (long long)(id >> 1) * EMB_DIM;   // packed row (two ids per row)
    const long long srow = (long long)(id >> 5) * EMB_DIM;   // group row (GROUP_SIZE=32)
    const int shift = (id & 1) * 4;                          // low nibble for even, high for odd
    const long long obase = (long long)token * EMB_DIM;

    int f = threadIdx.x * 4;                                 // 256 thr * 4 elems = 1024/iter
    #pragma unroll
    for (int it = 0; it < 4; ++it, f += 1024) {
        // weight stream: ~1.06x reuse -> bypass cache retention (nontemporal)
        const int4* wp = reinterpret_cast<const int4*>(&weight[wrow + f]);
        int4 w;
        w.x = __builtin_nontemporal_load(&((const int*)wp)[0]);
        w.y = __builtin_nontemporal_load(&((const int*)wp)[1]);
        w.z = __builtin_nontemporal_load(&((const int*)wp)[2]);
        w.w = __builtin_nontemporal_load(&((const int*)wp)[3]);
        // scale stream: 2.3x reuse across tokens -> keep cacheable
        float4 s = *reinterpret_cast<const float4*>(&scale[srow + f]);
        float4 o;
        o.x = (float)(((w.x >> shift) & 15) - 8) * s.x;
        o.y = (float)(((w.y >> shift) & 15) - 8) * s.y;
        o.z = (float)(((w.z >> shift) & 15) - 8) * s.z;
        o.w = (float)(((w.w >> shift) & 15) - 8) * s.w;
        // output: write-once stream -> nontemporal store
        float* op = &out[obase + f];
        __builtin_nontemporal_store(o.x, &op[0]);
        __builtin_nontemporal_store(o.y, &op[1]);
        __builtin_nontemporal_store(o.z, &op[2]);
        __builtin_nontemporal_store(o.w, &op[3]);
    }
}

extern "C" void kernel_launch(void* const* d_in, const int* in_sizes, int n_in,
                              void* d_out, int out_size, void* d_ws, size_t ws_size,
                              hipStream_t stream) {
    const int*   ids    = (const int*)d_in[0];
    const int*   weight = (const int*)d_in[1];
    const float* scale  = (const float*)d_in[2];
    float*       out    = (float*)d_out;

    const int n_tokens = in_sizes[0];          // 4 * 2048 = 8192
    qembed_kernel<<<n_tokens, 256, 0, stream>>>(ids, weight, scale, out, n_tokens);
}

// Round 3
// 61.154 us; speedup vs baseline: 1.0314x; 1.0037x over previous
//
#include <hip/hip_runtime.h>

#define EMB_DIM 4096

__global__ __launch_bounds__(256) void qembed_kernel(
    const int* __restrict__ ids,
    const int* __restrict__ weight,       // packed int4 pairs, widened to int32 (0..255)
    const float* __restrict__ scale,
    float* __restrict__ out,
    int n_tokens)
{
    const int token = blockIdx.x;
    if (token >= n_tokens) return;

    const int id = ids[token];
    const long long wrow = (long long)(id >> 1) * EMB_DIM;   // packed row (two ids per row)
    const long long srow = (long long)(id >> 5) * EMB_DIM;   // group row (GROUP_SIZE=32)
    const int shift = (id & 1) * 4;                          // low nibble for even, high for odd
    const long long obase = (long long)token * EMB_DIM;

    const int f0 = threadIdx.x * 4;

    // Phase 1: issue ALL loads first — 8 outstanding vmem ops per thread for
    // maximum memory-level parallelism on the scattered row fetches.
    int4   w[4];
    float4 s[4];
    #pragma unroll
    for (int it = 0; it < 4; ++it) {
        const int f = f0 + it * 1024;
        const int* wp = &weight[wrow + f];
        w[it].x = __builtin_nontemporal_load(&wp[0]);
        w[it].y = __builtin_nontemporal_load(&wp[1]);
        w[it].z = __builtin_nontemporal_load(&wp[2]);
        w[it].w = __builtin_nontemporal_load(&wp[3]);
        s[it] = *reinterpret_cast<const float4*>(&scale[srow + f]);
    }

    // Phase 2: dequant + store (nontemporal write-once stream).
    #pragma unroll
    for (int it = 0; it < 4; ++it) {
        const int f = f0 + it * 1024;
        float4 o;
        o.x = (float)(((w[it].x >> shift) & 15) - 8) * s[it].x;
        o.y = (float)(((w[it].y >> shift) & 15) - 8) * s[it].y;
        o.z = (float)(((w[it].z >> shift) & 15) - 8) * s[it].z;
        o.w = (float)(((w[it].w >> shift) & 15) - 8) * s[it].w;
        float* op = &out[obase + f];
        __builtin_nontemporal_store(o.x, &op[0]);
        __builtin_nontemporal_store(o.y, &op[1]);
        __builtin_nontemporal_store(o.z, &op[2]);
        __builtin_nontemporal_store(o.w, &op[3]);
    }
}

extern "C" void kernel_launch(void* const* d_in, const int* in_sizes, int n_in,
                              void* d_out, int out_size, void* d_ws, size_t ws_size,
                              hipStream_t stream) {
    const int*   ids    = (const int*)d_in[0];
    const int*   weight = (const int*)d_in[1];
    const float* scale  = (const float*)d_in[2];
    float*       out    = (float*)d_out;

    const int n_tokens = in_sizes[0];          // 4 * 2048 = 8192
    qembed_kernel<<<n_tokens, 256, 0, stream>>>(ids, weight, scale, out, n_tokens);
}